// Round 1
// baseline (828.110 us; speedup 1.0000x reference)
//
#include <hip/hip_runtime.h>
#include <hip/hip_bf16.h>

#define DIMK 64
#define NREL 16

__global__ void zero_denom_kernel(float* __restrict__ denom, int n) {
    int i = blockIdx.x * blockDim.x + threadIdx.x;
    if (i < n) denom[i] = 0.0f;
}

__device__ __forceinline__ float tanh_fast(float x) {
    // tanh(x) = 1 - 2/(exp(2x)+1); exp via v_exp_f32
    float e = __expf(2.0f * x);
    return 1.0f - 2.0f / (e + 1.0f);
}

// grid: 16 types x NCHUNK chunks. Block (type,c) scans chunk c of the edge
// list, processing only edges of its type. Each wave holds W[type]'s column
// `lane` in 64 VGPRs; per matched edge, src/dst are made wave-uniform via
// readlane so emb-row loads are scalar(broadcast) loads feeding the FMA loop.
__global__ __launch_bounds__(256)
void edge_att_kernel(const float* __restrict__ emb,
                     const float* __restrict__ rel,
                     const float* __restrict__ WR,
                     const int* __restrict__ esrc,
                     const int* __restrict__ edst,
                     const int* __restrict__ etype,
                     float* __restrict__ exbuf,   // aliases d_out; holds exp(att)
                     float* __restrict__ denom,
                     int E, int chunkSize) {
    const int type = blockIdx.x & 15;
    const int c    = blockIdx.x >> 4;
    const int lane = threadIdx.x & 63;
    const int wid  = threadIdx.x >> 6;

    long base0 = (long)c * (long)chunkSize;
    long cend  = base0 + chunkSize;
    if (cend > E) cend = E;
    if (base0 >= cend) return;

    int per = (chunkSize + 3) >> 2;   // 4 waves per block
    long wbeg = base0 + (long)wid * per;
    long wend = wbeg + per;
    if (wend > cend) wend = cend;
    if (wbeg >= wend) return;         // wid is wave-uniform -> uniform exit

    // W column for this type: w[d] = WR[type][d][lane]  (coalesced across lanes)
    float w[DIMK];
    const float* Wt = WR + (size_t)type * DIMK * DIMK;
    #pragma unroll
    for (int d = 0; d < DIMK; ++d) w[d] = Wt[d * DIMK + lane];
    const float rk = rel[type * DIMK + lane];

    for (long s0 = wbeg; s0 < wend; s0 += 64) {
        long e = s0 + lane;
        int ty = -1, sv = 0, dv = 0;
        if (e < wend) {
            ty = etype[e];
            sv = esrc[e];
            dv = edst[e];
        }
        unsigned long long m = __ballot(ty == type);
        while (m) {
            int b = __builtin_ctzll(m);     // uniform (m uniform from ballot)
            m &= m - 1;
            int sn = __builtin_amdgcn_readlane(sv, b);
            int dn = __builtin_amdgcn_readlane(dv, b);

            const float4* es4 = (const float4*)(emb + (size_t)sn * DIMK);
            const float4* ed4 = (const float4*)(emb + (size_t)dn * DIMK);

            float t0 = 0.f, t1 = 0.f, t2 = 0.f, t3 = 0.f;
            #pragma unroll
            for (int i = 0; i < DIMK / 4; ++i) {
                float4 a = es4[i];           // uniform addr -> s_load broadcast
                t0 = fmaf(a.x, w[4 * i + 0], t0);
                t1 = fmaf(a.y, w[4 * i + 1], t1);
                t2 = fmaf(a.z, w[4 * i + 2], t2);
                t3 = fmaf(a.w, w[4 * i + 3], t3);
            }
            float h0 = 0.f, h1 = 0.f, h2 = 0.f, h3 = 0.f;
            #pragma unroll
            for (int i = 0; i < DIMK / 4; ++i) {
                float4 a = ed4[i];
                h0 = fmaf(a.x, w[4 * i + 0], h0);
                h1 = fmaf(a.y, w[4 * i + 1], h1);
                h2 = fmaf(a.z, w[4 * i + 2], h2);
                h3 = fmaf(a.w, w[4 * i + 3], h3);
            }
            float t = (t0 + t1) + (t2 + t3);
            float h = (h0 + h1) + (h2 + h3);

            float p = t * tanh_fast(h + rk);  // lane k's term of the dot
            // wave64 butterfly sum
            #pragma unroll
            for (int off = 32; off > 0; off >>= 1)
                p += __shfl_xor(p, off);

            if (lane == 0) {
                float ex = __expf(p);         // att is O(0.1): no max-shift needed
                exbuf[s0 + b] = ex;
                atomicAdd(&denom[dn], ex);
            }
        }
    }
}

__global__ void normalize_kernel(float* __restrict__ out,
                                 const float* __restrict__ denom,
                                 const int* __restrict__ edst, int E) {
    int e = blockIdx.x * blockDim.x + threadIdx.x;
    if (e < E) out[e] = out[e] / denom[edst[e]];
}

extern "C" void kernel_launch(void* const* d_in, const int* in_sizes, int n_in,
                              void* d_out, int out_size, void* d_ws, size_t ws_size,
                              hipStream_t stream) {
    const float* emb  = (const float*)d_in[0];   // [n_nodes, 64]
    const float* rel  = (const float*)d_in[1];   // [16, 64]
    const float* WR   = (const float*)d_in[2];   // [16, 64, 64]
    const int*   esrc = (const int*)d_in[3];     // [E]
    const int*   edst = (const int*)d_in[4];     // [E]
    const int*   ety  = (const int*)d_in[5];     // [E]

    const int E       = in_sizes[3];
    const int n_nodes = in_sizes[0] / DIMK;

    float* out   = (float*)d_out;   // [E]
    float* denom = (float*)d_ws;    // [n_nodes] scratch (ws poisoned each call)

    zero_denom_kernel<<<(n_nodes + 255) / 256, 256, 0, stream>>>(denom, n_nodes);

    const int NCHUNK = 256;
    int chunk = (E + NCHUNK - 1) / NCHUNK;
    edge_att_kernel<<<16 * NCHUNK, 256, 0, stream>>>(emb, rel, WR, esrc, edst, ety,
                                                     out, denom, E, chunk);

    normalize_kernel<<<(E + 255) / 256, 256, 0, stream>>>(out, denom, edst, E);
}